// Round 10
// baseline (343.579 us; speedup 1.0000x reference)
//
#include <hip/hip_runtime.h>
#include <hip/hip_bf16.h>

typedef __bf16 bf16x8 __attribute__((ext_vector_type(8)));
typedef float  f32x4  __attribute__((ext_vector_type(4)));

static constexpr int S  = 64;    // DIM_S
static constexpr int C  = 8;     // DIM_C (experts)
static constexpr int HD = 256;   // hidden width

__device__ __forceinline__ unsigned short f2bf(float f) {
  __hip_bfloat16 b = __float2bfloat16(f);
  unsigned short u;
  __builtin_memcpy(&u, &b, 2);
  return u;
}
__device__ __forceinline__ float bfhi2f(unsigned int hi16) {  // bits already in [31:16]
  float f;
  __builtin_memcpy(&f, &hi16, 4);
  return f;
}

// async global->LDS DMA, 16 B per lane; lds dest = wave-uniform base + lane*16
__device__ __forceinline__ void gl2lds16(const void* g, void* l) {
  __builtin_amdgcn_global_load_lds(
      (const __attribute__((address_space(1))) unsigned int*)g,
      (__attribute__((address_space(3))) unsigned int*)l, 16, 0, 0);
}

// LDS-tiled transposes, coalesced both sides.
// blocks 0..511:  W2 [C][256k][256n] -> W2T bf16 [C][256n][256k]
// blocks 512..639: W1 [C][64s][256h] -> W1T bf16 [C][256h][64s]
__global__ __launch_bounds__(256) void prep_weights(
    const float* __restrict__ W1, const float* __restrict__ W2,
    unsigned short* __restrict__ W1T, unsigned short* __restrict__ W2T)
{
  __shared__ float tile[32][33];
  const int tid = threadIdx.x, cl = tid & 31, r0 = tid >> 5;
  const int b = blockIdx.x;
  if (b < 512) {
    const int c = b >> 6, t = b & 63, kt = t >> 3, nt = t & 7;
    const float* src = W2 + c * 65536;
    #pragma unroll
    for (int i = 0; i < 4; ++i) {
      int r = r0 + 8 * i;
      tile[r][cl] = src[(kt * 32 + r) * 256 + nt * 32 + cl];
    }
    __syncthreads();
    unsigned short* dst = W2T + c * 65536;
    #pragma unroll
    for (int i = 0; i < 4; ++i) {
      int r = r0 + 8 * i;
      dst[(nt * 32 + r) * 256 + kt * 32 + cl] = f2bf(tile[cl][r]);
    }
  } else {
    const int bb = b - 512;
    const int c = bb >> 4, t = bb & 15, st2 = t >> 3, ht = t & 7;
    const float* src = W1 + c * 16384;
    #pragma unroll
    for (int i = 0; i < 4; ++i) {
      int r = r0 + 8 * i;
      tile[r][cl] = src[(st2 * 32 + r) * 256 + ht * 32 + cl];
    }
    __syncthreads();
    unsigned short* dst = W1T + c * 16384;
    #pragma unroll
    for (int i = 0; i < 4; ++i) {
      int r = r0 + 8 * i;
      dst[(ht * 32 + r) * 64 + st2 * 32 + cl] = f2bf(tile[cl][r]);
    }
  }
}

// One block: 256 batch rows x 1 expert. 4 waves, 64 rows/wave.
// R8 structure with a 3-blocks/CU occupancy budget:
//   sT shrunk to 20 KB (32-hidden half-quarter transpose slices, LDT=40)
//   LDS = sU 32768 + sT 20480 = 53248 B -> 3 blocks/CU (159.7/160 KB)
//   __launch_bounds__(256,3): VGPR cap ~170; pb2/pw3 packed bf16 to fit
__global__ __launch_bounds__(256, 3) void moe_fused(
    const float* __restrict__ st,
    const unsigned short* __restrict__ W1T,
    const unsigned short* __restrict__ W2T,
    const float* __restrict__ b1,
    const float* __restrict__ b2,
    const float* __restrict__ W3,
    const float* __restrict__ b3,
    float* __restrict__ out)
{
  constexpr int LDT = 40;   // sT pitch: 32 hidden + 8 pad bf16 (80 B rows)

  // sU: phase 1 = st tile bf16 [256 rows][64], granule-swizzled (g^(r&7));
  //     phase 2 = W2 ping-pong 2 x (32 rows x 256 bf16), same swizzle.
  __shared__ __align__(16) unsigned short sU[2 * 32 * 256];  // 32768 B
  __shared__ __align__(16) unsigned short sT[256 * LDT];     // 20480 B

  const int tid  = threadIdx.x;
  const int lane = tid & 63;
  const int wv   = tid >> 6;          // wave -> batch rows [wv*64, wv*64+64)
  const int l15  = lane & 15;
  const int q    = lane >> 4;
  const int c    = blockIdx.x >> 8;
  const int row0 = (blockIdx.x & 255) * 256;

  const unsigned short* W1c = W1T + c * HD * S;
  const unsigned short* W2c = W2T + c * HD * HD;

  // ---- stage st (fp32 -> bf16) into sU; wave-private rows, swizzled ----
  #pragma unroll
  for (int it = 0; it < 8; ++it) {
    const int r = wv * 64 + it * 8 + (lane >> 3);   // block-local batch row
    const int g = lane & 7;                          // logical 16B granule
    const float4* p = reinterpret_cast<const float4*>(
        st + (size_t)(row0 + r) * S + g * 8);
    float4 x = p[0], y = p[1];
    union { uint4 u4; unsigned short us[8]; } pk;
    pk.us[0] = f2bf(x.x); pk.us[1] = f2bf(x.y); pk.us[2] = f2bf(x.z); pk.us[3] = f2bf(x.w);
    pk.us[4] = f2bf(y.x); pk.us[5] = f2bf(y.y); pk.us[6] = f2bf(y.z); pk.us[7] = f2bf(y.w);
    *reinterpret_cast<uint4*>(sU + r * 64 + ((g ^ (r & 7)) << 3)) = pk.u4;
  }
  __asm__ __volatile__("s_waitcnt lgkmcnt(0)" ::: "memory");

  // ---- phase 1: h1^T = W1^T @ st^T (16x16x32), 4 quarters of 64 hidden ----
  bf16x8 aF[4][4][2];  // [cc][rt][k2]: phase-2 A-frags (m=batch l15, k=hidden)
  #pragma unroll
  for (int cc = 0; cc < 4; ++cc) {
    f32x4 bias[4];
    #pragma unroll
    for (int mt = 0; mt < 4; ++mt)
      bias[mt] = *reinterpret_cast<const f32x4*>(
          b1 + c * HD + cc * 64 + mt * 16 + q * 4);

    f32x4 acc[4][4];   // [mt(hidden)][nt(batch)]
    #pragma unroll
    for (int mt = 0; mt < 4; ++mt)
      #pragma unroll
      for (int nt = 0; nt < 4; ++nt)
        acc[mt][nt] = (f32x4){0.f, 0.f, 0.f, 0.f};

    #pragma unroll
    for (int ks = 0; ks < 2; ++ks) {
      bf16x8 aW[4];
      #pragma unroll
      for (int mt = 0; mt < 4; ++mt)
        aW[mt] = *reinterpret_cast<const bf16x8*>(
            W1c + (cc * 64 + mt * 16 + l15) * S + ks * 32 + q * 8);
      bf16x8 bB[4];
      #pragma unroll
      for (int nt = 0; nt < 4; ++nt) {
        const int r = wv * 64 + nt * 16 + l15;
        const int g = ks * 4 + q;
        bB[nt] = *reinterpret_cast<const bf16x8*>(
            sU + r * 64 + ((g ^ (r & 7)) << 3));
      }
      #pragma unroll
      for (int mt = 0; mt < 4; ++mt)
        #pragma unroll
        for (int nt = 0; nt < 4; ++nt)
          acc[mt][nt] = __builtin_amdgcn_mfma_f32_16x16x32_bf16(
              aW[mt], bB[nt], acc[mt][nt], 0, 0, 0);
    }

    // epilogue: +bias, relu, C->A transpose in TWO 32-hidden halves through
    // this wave's OWN sT rows (wave-private: lgkm drains, no barrier).
    #pragma unroll
    for (int hh = 0; hh < 2; ++hh) {
      #pragma unroll
      for (int mtl = 0; mtl < 2; ++mtl) {
        const int mt = hh * 2 + mtl;
        #pragma unroll
        for (int nt = 0; nt < 4; ++nt) {
          ushort4 pk;
          float v0 = acc[mt][nt][0] + bias[mt][0]; v0 = v0 > 0.f ? v0 : 0.f;
          float v1 = acc[mt][nt][1] + bias[mt][1]; v1 = v1 > 0.f ? v1 : 0.f;
          float v2 = acc[mt][nt][2] + bias[mt][2]; v2 = v2 > 0.f ? v2 : 0.f;
          float v3 = acc[mt][nt][3] + bias[mt][3]; v3 = v3 > 0.f ? v3 : 0.f;
          pk.x = f2bf(v0); pk.y = f2bf(v1); pk.z = f2bf(v2); pk.w = f2bf(v3);
          *reinterpret_cast<ushort4*>(
              sT + (wv * 64 + nt * 16 + l15) * LDT + mtl * 16 + q * 4) = pk;
        }
      }
      __asm__ __volatile__("s_waitcnt lgkmcnt(0)" ::: "memory");
      #pragma unroll
      for (int rt = 0; rt < 4; ++rt)
        aF[cc][rt][hh] = *reinterpret_cast<const bf16x8*>(
            sT + (wv * 64 + rt * 16 + l15) * LDT + q * 8);
      __asm__ __volatile__("s_waitcnt lgkmcnt(0)" ::: "memory");  // WAR guard
    }
  }

  // ---- phase-2/3 scalars, packed bf16 (b2 | W3<<16): 16 regs not 32 ----
  unsigned int pbw[8][2];
  #pragma unroll
  for (int ch = 0; ch < 8; ++ch)
    #pragma unroll
    for (int ct = 0; ct < 2; ++ct) {
      const int n = ch * 32 + ct * 16 + l15;
      pbw[ch][ct] = (unsigned int)f2bf(b2[c * HD + n]) |
                    ((unsigned int)f2bf(W3[c * HD + n]) << 16);
    }
  const float bb3 = b3[c];

  __syncthreads();   // barrier #1: ALL waves done reading sU-as-st

  // ---- DMA prologue: W2 chunks 0,1 into sU (now free) ----
  #pragma unroll
  for (int pc = 0; pc < 2; ++pc) {
    unsigned short* buf = sU + pc * (32 * 256);
    #pragma unroll
    for (int i = 0; i < 4; ++i) {
      const int b2i = wv * 4 + i;            // 1KB unit (2 rows)
      const int r   = b2i * 2 + (lane >> 5); // local row 0..31
      const int j   = (lane & 31) ^ (r & 7); // logical granule
      gl2lds16(W2c + (pc * 32 + r) * 256 + j * 8, buf + b2i * 512);
    }
  }
  __syncthreads();   // barrier #2: drains vmcnt(0) -> chunks 0,1 landed

  // ---- phase 2+3: d = relu(h1 @ W2 + b2) . W3, chunk ping-pong ----
  float dacc[4][4];
  #pragma unroll
  for (int rt = 0; rt < 4; ++rt)
    #pragma unroll
    for (int r = 0; r < 4; ++r) dacc[rt][r] = 0.f;

  #pragma unroll
  for (int ch = 0; ch < 8; ++ch) {
    const unsigned short* buf = sU + (ch & 1) * (32 * 256);

    f32x4 acc[4][2];
    #pragma unroll
    for (int rt = 0; rt < 4; ++rt)
      #pragma unroll
      for (int ct = 0; ct < 2; ++ct)
        acc[rt][ct] = (f32x4){0.f, 0.f, 0.f, 0.f};

    #pragma unroll
    for (int ks = 0; ks < 8; ++ks) {
      const int jj = ks * 4 + q;            // logical granule of this k-slice
      const int cc = ks >> 1, k2 = ks & 1;
      #pragma unroll
      for (int ct = 0; ct < 2; ++ct) {
        const int nl = ct * 16 + l15;       // local row (= h2 col within chunk)
        bf16x8 b = *reinterpret_cast<const bf16x8*>(
            buf + nl * 256 + ((jj ^ (l15 & 7)) << 3));
        #pragma unroll
        for (int rt = 0; rt < 4; ++rt)
          acc[rt][ct] = __builtin_amdgcn_mfma_f32_16x16x32_bf16(
              aF[cc][rt][k2], b, acc[rt][ct], 0, 0, 0);
      }
    }

    // fused epilogue: relu(h2 + b2) dot W3 per row (operands unpacked from regs)
    #pragma unroll
    for (int ct = 0; ct < 2; ++ct) {
      const unsigned int p = pbw[ch][ct];
      const float bias = bfhi2f(p << 16);
      const float w3v  = bfhi2f(p & 0xffff0000u);
      #pragma unroll
      for (int rt = 0; rt < 4; ++rt)
        #pragma unroll
        for (int r = 0; r < 4; ++r) {
          float v = acc[rt][ct][r] + bias;
          v = v > 0.f ? v : 0.f;
          dacc[rt][r] += v * w3v;
        }
    }

    __syncthreads();   // readers of buf[ch&1] done; drains chunk ch+1's DMA
    if (ch < 6) {      // refill freed buffer with chunk ch+2 (1 chunk in flight)
      unsigned short* nbuf = sU + (ch & 1) * (32 * 256);
      #pragma unroll
      for (int i = 0; i < 4; ++i) {
        const int b2i = wv * 4 + i;
        const int r   = b2i * 2 + (lane >> 5);
        const int j   = (lane & 31) ^ (r & 7);
        gl2lds16(W2c + ((ch + 2) * 32 + r) * 256 + j * 8, nbuf + b2i * 512);
      }
    }
  }

  // ---- reduce over the 16 col-lanes, write out ----
  #pragma unroll
  for (int rt = 0; rt < 4; ++rt)
    #pragma unroll
    for (int r = 0; r < 4; ++r) {
      float v = dacc[rt][r];
      v += __shfl_xor(v, 1);
      v += __shfl_xor(v, 2);
      v += __shfl_xor(v, 4);
      v += __shfl_xor(v, 8);
      dacc[rt][r] = v;
    }

  if (l15 == 0) {
    const int rbase = row0 + wv * 64 + q * 4;
    #pragma unroll
    for (int rt = 0; rt < 4; ++rt)
      #pragma unroll
      for (int r = 0; r < 4; ++r)
        out[(rbase + rt * 16 + r) * C + c] = dacc[rt][r] + bb3;
  }
}

extern "C" void kernel_launch(void* const* d_in, const int* in_sizes, int n_in,
                              void* d_out, int out_size, void* d_ws, size_t ws_size,
                              hipStream_t stream)
{
  const float* st = (const float*)d_in[0];
  const float* W1 = (const float*)d_in[1];
  const float* b1 = (const float*)d_in[2];
  const float* W2 = (const float*)d_in[3];
  const float* b2 = (const float*)d_in[4];
  const float* W3 = (const float*)d_in[5];
  const float* b3 = (const float*)d_in[6];
  float* out = (float*)d_out;

  unsigned short* W1T = (unsigned short*)d_ws;         // 131072 bf16
  unsigned short* W2T = W1T + C * HD * S;              // 524288 bf16

  prep_weights<<<dim3(640), dim3(256), 0, stream>>>(W1, W2, W1T, W2T);
  moe_fused<<<dim3(2048), dim3(256), 0, stream>>>(st, W1T, W2T, b1, b2, W3, b3, out);
}

// Round 11
// 226.378 us; speedup vs baseline: 1.5177x; 1.5177x over previous
//
#include <hip/hip_runtime.h>
#include <hip/hip_bf16.h>

typedef __bf16 bf16x8 __attribute__((ext_vector_type(8)));
typedef float  f32x4  __attribute__((ext_vector_type(4)));

static constexpr int S  = 64;    // DIM_S
static constexpr int C  = 8;     // DIM_C (experts)
static constexpr int HD = 256;   // hidden width

__device__ __forceinline__ unsigned short f2bf(float f) {
  __hip_bfloat16 b = __float2bfloat16(f);
  unsigned short u;
  __builtin_memcpy(&u, &b, 2);
  return u;
}

// Fragment-major weight prep. One WAVE produces one 1 KB fragment group
// (64 lanes x 16 B, fully coalesced write).
//   W2F group (c, nt 0..15, ks 0..7):  lane(q*16+l15) j-th elem =
//       W2[c][k=ks*32+q*8+j][n=nt*16+l15]      (B-frag for 16x16x32)
//   W1F group (c, ht 0..15, ks 0..1):  lane(q*16+l15) j-th elem =
//       W1[c][s=ks*32+q*8+j][h=ht*16+l15]      (A-frag for 16x16x32)
// 1024 W2F groups + 256 W1F groups = 1280 waves = 320 blocks.
__global__ __launch_bounds__(256) void prep_frag(
    const float* __restrict__ W1, const float* __restrict__ W2,
    unsigned short* __restrict__ W1F, unsigned short* __restrict__ W2F)
{
  const int lane = threadIdx.x & 63;
  const int gid  = blockIdx.x * 4 + (threadIdx.x >> 6);
  const int q = lane >> 4, l15 = lane & 15;
  union { uint4 u4; unsigned short us[8]; } pk;
  if (gid < 1024) {
    const int c = gid >> 7, rem = gid & 127, nt = rem >> 3, ks = rem & 7;
    const float* src = W2 + c * 65536 + nt * 16 + l15;
    #pragma unroll
    for (int j = 0; j < 8; ++j)
      pk.us[j] = f2bf(src[(ks * 32 + q * 8 + j) * 256]);
    *reinterpret_cast<uint4*>(W2F + gid * 512 + lane * 8) = pk.u4;
  } else {
    const int g = gid - 1024;
    const int c = g >> 5, rem = g & 31, ht = rem >> 1, ks = rem & 1;
    const float* src = W1 + c * 16384 + ht * 16 + l15;
    #pragma unroll
    for (int j = 0; j < 8; ++j)
      pk.us[j] = f2bf(src[(ks * 32 + q * 8 + j) * 256]);
    *reinterpret_cast<uint4*>(W1F + g * 512 + lane * 8) = pk.u4;
  }
}

// One block: 256 batch rows x 1 expert. 4 waves, 64 rows/wave.
// ZERO __syncthreads: st stage + h1 transpose are wave-private (lgkm drains);
// phase-1 A-frags and phase-2 B-frags are coalesced 1KB global loads from the
// fragment-major W1F/W2F (L1/L2-hot under the c-major grid; 2 blocks/CU share
// one expert). Registers ~250/wave -> 2 waves/SIMD (proven floor: R3/R10
// spill when pushed to 3). LDS = sU 32768 + sT 36864 = 69632 B.
__global__ __launch_bounds__(256, 2) void moe_fused(
    const float* __restrict__ st,
    const unsigned short* __restrict__ W1F,
    const unsigned short* __restrict__ W2F,
    const float* __restrict__ b1,
    const float* __restrict__ b2,
    const float* __restrict__ W3,
    const float* __restrict__ b3,
    float* __restrict__ out)
{
  constexpr int LDT = 72;   // sT pitch: 64 + 8 pad bf16

  // sU: st tile bf16 [256 rows][64], granule-swizzled (g^(r&7)). 32768 B.
  __shared__ __align__(16) unsigned short sU[256 * 64];
  __shared__ __align__(16) unsigned short sT[256 * LDT];   // 36864 B

  const int tid  = threadIdx.x;
  const int lane = tid & 63;
  const int wv   = tid >> 6;          // wave -> batch rows [wv*64, wv*64+64)
  const int l15  = lane & 15;
  const int q    = lane >> 4;
  const int c    = blockIdx.x >> 8;
  const int row0 = (blockIdx.x & 255) * 256;

  const unsigned short* W1c = W1F + c * 16384;   // 32 groups x 512
  const unsigned short* W2c = W2F + c * 65536;   // 128 groups x 512
  const float bb3 = b3[c];

  // ---- stage st (fp32 -> bf16) into sU; wave-private rows, swizzled ----
  #pragma unroll
  for (int it = 0; it < 8; ++it) {
    const int r = wv * 64 + it * 8 + (lane >> 3);   // block-local batch row
    const int g = lane & 7;                          // logical 16B granule
    const float4* p = reinterpret_cast<const float4*>(
        st + (size_t)(row0 + r) * S + g * 8);
    float4 x = p[0], y = p[1];
    union { uint4 u4; unsigned short us[8]; } pk;
    pk.us[0] = f2bf(x.x); pk.us[1] = f2bf(x.y); pk.us[2] = f2bf(x.z); pk.us[3] = f2bf(x.w);
    pk.us[4] = f2bf(y.x); pk.us[5] = f2bf(y.y); pk.us[6] = f2bf(y.z); pk.us[7] = f2bf(y.w);
    *reinterpret_cast<uint4*>(sU + r * 64 + ((g ^ (r & 7)) << 3)) = pk.u4;
  }
  __asm__ __volatile__("s_waitcnt lgkmcnt(0)" ::: "memory");

  // ---- phase 1: h1^T = W1^T @ st^T (16x16x32), 4 quarters of 64 hidden ----
  bf16x8 aF[4][4][2];  // [cc][rt][k2]: phase-2 A-frags (m=batch l15, k=hidden)
  #pragma unroll
  for (int cc = 0; cc < 4; ++cc) {
    f32x4 bias[4];
    #pragma unroll
    for (int mt = 0; mt < 4; ++mt)
      bias[mt] = *reinterpret_cast<const f32x4*>(
          b1 + c * HD + cc * 64 + mt * 16 + q * 4);

    f32x4 acc[4][4];   // [mt(hidden)][nt(batch)]
    #pragma unroll
    for (int mt = 0; mt < 4; ++mt)
      #pragma unroll
      for (int nt = 0; nt < 4; ++nt)
        acc[mt][nt] = (f32x4){0.f, 0.f, 0.f, 0.f};

    #pragma unroll
    for (int ks = 0; ks < 2; ++ks) {
      // A-frags: coalesced 1KB fragment-group loads (ht = cc*4+mt)
      bf16x8 aW[4];
      #pragma unroll
      for (int mt = 0; mt < 4; ++mt)
        aW[mt] = *reinterpret_cast<const bf16x8*>(
            W1c + ((cc * 4 + mt) * 2 + ks) * 512 + lane * 8);
      // B-frags: st rows (batch as N) from swizzled sU
      bf16x8 bB[4];
      #pragma unroll
      for (int nt = 0; nt < 4; ++nt) {
        const int r = wv * 64 + nt * 16 + l15;
        const int g = ks * 4 + q;
        bB[nt] = *reinterpret_cast<const bf16x8*>(
            sU + r * 64 + ((g ^ (r & 7)) << 3));
      }
      #pragma unroll
      for (int mt = 0; mt < 4; ++mt)
        #pragma unroll
        for (int nt = 0; nt < 4; ++nt)
          acc[mt][nt] = __builtin_amdgcn_mfma_f32_16x16x32_bf16(
              aW[mt], bB[nt], acc[mt][nt], 0, 0, 0);
    }

    // epilogue: +bias, relu, pack 4 consecutive hidden -> one b64 write;
    // C->A transpose through this wave's OWN sT rows (wave-private, no barrier)
    #pragma unroll
    for (int mt = 0; mt < 4; ++mt) {
      #pragma unroll
      for (int nt = 0; nt < 4; ++nt) {
        ushort4 pk;
        float v0 = acc[mt][nt][0] + bias[mt][0]; v0 = v0 > 0.f ? v0 : 0.f;
        float v1 = acc[mt][nt][1] + bias[mt][1]; v1 = v1 > 0.f ? v1 : 0.f;
        float v2 = acc[mt][nt][2] + bias[mt][2]; v2 = v2 > 0.f ? v2 : 0.f;
        float v3 = acc[mt][nt][3] + bias[mt][3]; v3 = v3 > 0.f ? v3 : 0.f;
        pk.x = f2bf(v0); pk.y = f2bf(v1); pk.z = f2bf(v2); pk.w = f2bf(v3);
        *reinterpret_cast<ushort4*>(
            sT + (wv * 64 + nt * 16 + l15) * LDT + mt * 16 + q * 4) = pk;
      }
    }
    __asm__ __volatile__("s_waitcnt lgkmcnt(0)" ::: "memory");
    #pragma unroll
    for (int rt = 0; rt < 4; ++rt)
      #pragma unroll
      for (int k2 = 0; k2 < 2; ++k2)
        aF[cc][rt][k2] = *reinterpret_cast<const bf16x8*>(
            sT + (wv * 64 + rt * 16 + l15) * LDT + k2 * 32 + q * 8);
    __asm__ __volatile__("s_waitcnt lgkmcnt(0)" ::: "memory");  // WAR guard
  }

  // ---- phase 2+3: d = relu(h1 @ W2 + b2) . W3 — no LDS, no barriers ----
  // B-frags: coalesced 1KB group loads from W2F, L1-hot (16 KB chunk shared
  // by the CU's 8 resident waves, all on the same expert).
  float dacc[4][4];
  #pragma unroll
  for (int rt = 0; rt < 4; ++rt)
    #pragma unroll
    for (int r = 0; r < 4; ++r) dacc[rt][r] = 0.f;

  #pragma unroll 2
  for (int ch = 0; ch < 8; ++ch) {
    float pb2v[2], pw3v[2];
    #pragma unroll
    for (int ct = 0; ct < 2; ++ct) {
      const int n = ch * 32 + ct * 16 + l15;
      pb2v[ct] = b2[c * HD + n];
      pw3v[ct] = W3[c * HD + n];
    }

    f32x4 acc[4][2];
    #pragma unroll
    for (int rt = 0; rt < 4; ++rt)
      #pragma unroll
      for (int ct = 0; ct < 2; ++ct)
        acc[rt][ct] = (f32x4){0.f, 0.f, 0.f, 0.f};

    #pragma unroll
    for (int ks = 0; ks < 8; ++ks) {
      const int cc = ks >> 1, k2 = ks & 1;
      #pragma unroll
      for (int ct = 0; ct < 2; ++ct) {
        bf16x8 bW = *reinterpret_cast<const bf16x8*>(
            W2c + ((ch * 2 + ct) * 8 + ks) * 512 + lane * 8);
        #pragma unroll
        for (int rt = 0; rt < 4; ++rt)
          acc[rt][ct] = __builtin_amdgcn_mfma_f32_16x16x32_bf16(
              aF[cc][rt][k2], bW, acc[rt][ct], 0, 0, 0);
      }
    }

    // fused epilogue: relu(h2 + b2) dot W3 per row
    #pragma unroll
    for (int ct = 0; ct < 2; ++ct) {
      const float bias = pb2v[ct];
      const float w3v  = pw3v[ct];
      #pragma unroll
      for (int rt = 0; rt < 4; ++rt)
        #pragma unroll
        for (int r = 0; r < 4; ++r) {
          float v = acc[rt][ct][r] + bias;
          v = v > 0.f ? v : 0.f;
          dacc[rt][r] += v * w3v;
        }
    }
  }

  // ---- reduce over the 16 col-lanes, write out ----
  #pragma unroll
  for (int rt = 0; rt < 4; ++rt)
    #pragma unroll
    for (int r = 0; r < 4; ++r) {
      float v = dacc[rt][r];
      v += __shfl_xor(v, 1);
      v += __shfl_xor(v, 2);
      v += __shfl_xor(v, 4);
      v += __shfl_xor(v, 8);
      dacc[rt][r] = v;
    }

  if (l15 == 0) {
    const int rbase = row0 + wv * 64 + q * 4;
    #pragma unroll
    for (int rt = 0; rt < 4; ++rt)
      #pragma unroll
      for (int r = 0; r < 4; ++r)
        out[(rbase + rt * 16 + r) * C + c] = dacc[rt][r] + bb3;
  }
}

extern "C" void kernel_launch(void* const* d_in, const int* in_sizes, int n_in,
                              void* d_out, int out_size, void* d_ws, size_t ws_size,
                              hipStream_t stream)
{
  const float* st = (const float*)d_in[0];
  const float* W1 = (const float*)d_in[1];
  const float* b1 = (const float*)d_in[2];
  const float* W2 = (const float*)d_in[3];
  const float* b2 = (const float*)d_in[4];
  const float* W3 = (const float*)d_in[5];
  const float* b3 = (const float*)d_in[6];
  float* out = (float*)d_out;

  unsigned short* W1F = (unsigned short*)d_ws;         // 131072 bf16 (256 KB)
  unsigned short* W2F = W1F + C * 16384;               // 524288 bf16 (1 MB)

  prep_frag<<<dim3(320), dim3(256), 0, stream>>>(W1, W2, W1F, W2F);
  moe_fused<<<dim3(2048), dim3(256), 0, stream>>>(st, W1F, W2F, b1, b2, W3, b3, out);
}